// Round 6
// baseline (2391.340 us; speedup 1.0000x reference)
//
#include <hip/hip_runtime.h>

typedef __attribute__((ext_vector_type(8))) _Float16 half8;
typedef __attribute__((ext_vector_type(4))) _Float16 half4;
typedef __attribute__((ext_vector_type(4))) float f32x4;

#define N_NODES 6272
#define CDIM    2048
#define ODIM    512
#define NP      25      // 256-row panels (ceil 6272/256)
#define NT      25      // 256-col tiles
#define NSLOT   200     // 25 tiles * 8 candidates per node

// brick scheduling: 28 bricks of 4p x 8t tiles; XCD x owns bricks {x, x+8, x+16, x+24}
#define NBRICK  28
#define GRAM_GRID 896   // 112 bids per XCD * 8

// ---------------- workspace layout (bytes) ----------------
#define XHI_OFF    0ul
#define XLO_OFF    25690112ul
#define CANDV_OFF  51380224ul
#define CANDI_OFF  56397824ul
#define SQ_OFF     61415424ul
#define KNN_OFF    61440512ul
#define DEG_OFF    61641216ul
#define CNT_OFF    61666304ul
#define DINV_OFF   61691392ul
#define RPTR_OFF   61716480ul
#define COL_OFF    61741824ul
#define W1T_OFF    61967616ul
#define W2T_OFF    64064768ul
// hw (f32, 12.8MB) and h1h (fp16, 6.4MB) reuse the XLO region after gram is done
#define HW_OFF     XLO_OFF
#define H1H_OFF    (XLO_OFF + 12845056ul)

// ---------------- async global->LDS (16B per lane, wave-uniform LDS base) ----
__device__ __forceinline__ void gld_lds16(const void* g, void* l) {
    __builtin_amdgcn_global_load_lds(
        (const __attribute__((address_space(1))) void*)g,
        (__attribute__((address_space(3))) void*)l, 16, 0, 0);
}

// ======== BK=64 helpers (hgemm) ========
// MFMA fragment read from a [rows][64 f16] tile with 16B-block XOR-(row&7) swizzle
__device__ __forceinline__ half8 frag_read(const char* base, int row, int s, int lane) {
    int b = (s * 4 + (lane >> 4)) ^ (row & 7);
    return *(const half8*)(base + row * 128 + b * 16);
}

// ======== BK=32 helpers (gram) ========
// tile layout [rows][32 f16 = 64B], 16B block b holds global k-block b ^ S(row),
// S(row) = (row&3) ^ ((row>>2)&3)
__device__ __forceinline__ half8 frag_read32(const char* tile, int row, int lane) {
    int b = ((lane >> 4) ^ (row & 3) ^ ((row >> 2) & 3)) & 3;
    return *(const half8*)(tile + row * 64 + b * 16);
}

// stage rows [wsub*128, +128) of a 256x32 f16 tile: 8 gld_lds16 per lane.
__device__ __forceinline__ void stage32(char* tile, const _Float16* src,
                                        size_t row0, int kk, int lane, int wsub) {
    int r_in = lane >> 2;
    int kb = (lane & 3) ^ (r_in & 3) ^ ((r_in >> 2) & 3);
#pragma unroll
    for (int g = 0; g < 8; g++) {
        int R = wsub * 128 + g * 16;
        const _Float16* gp = src + (row0 + (size_t)(R + r_in)) * CDIM + kk + kb * 8;
        gld_lds16(gp, tile + R * 64);
    }
}

// ---------------- x -> (hi, lo) fp16 split ----------------
__global__ __launch_bounds__(256) void conv_split_kernel(const float* __restrict__ x,
        _Float16* __restrict__ xhi, _Float16* __restrict__ xlo) {
    size_t idx = ((size_t)blockIdx.x * 256 + threadIdx.x) * 4;
    float4 v = *(const float4*)(x + idx);
    float vv[4] = {v.x, v.y, v.z, v.w};
    half4 h, l;
#pragma unroll
    for (int j = 0; j < 4; j++) {
        _Float16 hj = (_Float16)vv[j];
        h[j] = hj;
        l[j] = (_Float16)(vv[j] - (float)hj);
    }
    *(half4*)(xhi + idx) = h;
    *(half4*)(xlo + idx) = l;
}

// ---------------- W [K][N] f32 -> Wt [N][K] f16 ----------------
__global__ __launch_bounds__(256) void wtrans_kernel(const float* __restrict__ W,
        _Float16* __restrict__ Wt, int K, int N) {
    __shared__ float tile[64][65];
    int kb = blockIdx.x * 64, nb = blockIdx.y * 64;
    int tid = threadIdx.x;
    int r = tid >> 2, c0 = (tid & 3) * 16;
#pragma unroll
    for (int u = 0; u < 4; u++) {
        float4 v = *(const float4*)(W + (size_t)(kb + r) * N + nb + c0 + u * 4);
        tile[r][c0 + u * 4 + 0] = v.x; tile[r][c0 + u * 4 + 1] = v.y;
        tile[r][c0 + u * 4 + 2] = v.z; tile[r][c0 + u * 4 + 3] = v.w;
    }
    __syncthreads();
    int rn = tid >> 2, ck0 = (tid & 3) * 16;
#pragma unroll
    for (int u = 0; u < 4; u++) {
        half4 o;
#pragma unroll
        for (int j = 0; j < 4; j++) o[j] = (_Float16)tile[ck0 + u * 4 + j][rn];
        *(half4*)(Wt + (size_t)(nb + rn) * K + kb + ck0 + u * 4) = o;
    }
}

// ---------------- sq[i] = sum_c x[i][c]^2 (fp32, exact vs ref) ----------------
__global__ __launch_bounds__(64) void sq_kernel(const float* __restrict__ x,
                                                float* __restrict__ sq) {
    int i = blockIdx.x;
    int t = threadIdx.x;
    const float* row = x + (size_t)i * CDIM;
    float s = 0.f;
#pragma unroll
    for (int k = 0; k < CDIM / 256; k++) {
        float4 v = *(const float4*)(row + (k * 64 + t) * 4);
        s += v.x * v.x + v.y * v.y + v.z * v.z + v.w * v.w;
    }
#pragma unroll
    for (int off = 32; off; off >>= 1) s += __shfl_down(s, off, 64);
    if (t == 0) sq[i] = s;
}

// ---------- fused MFMA Gram (256x256 tiles, brick-scheduled) + row top-8 ----------
// dot = hi.hi + hi.lo + lo.hi ; grid = 896 (28 bricks x 32 + dead pads).
// Brick = 4p x 8t tiles; all 32 blocks of a brick run concurrently on ONE XCD
// (bid&7 -> XCD round-robin inverted), so the brick's 12 panels' K-window stays
// L2-resident: staging goes from ~1.2 TB/s (L3) to L2 rate.
// All acc[][] indices compile-time (rule #20).
__global__ __launch_bounds__(512, 2) void gram_topk_mfma(
        const _Float16* __restrict__ xhi, const _Float16* __restrict__ xlo,
        const float* __restrict__ sq,
        float* __restrict__ candv, int* __restrict__ candi) {
    __shared__ char lds[131072];       // 2 bufs x {Ahi,Alo,Bhi,Blo} x 16KB; S unions
    __shared__ float topv[256][9];
    __shared__ int   topi[256][9];

    int tid = threadIdx.x, lane = tid & 63, wave = tid >> 6;
    int wr = wave >> 1, wc = wave & 1;
    int l15 = lane & 15, kg = lane >> 4;

    // brick mapping: xcd = bid&7 owns bricks {xcd, xcd+8, xcd+16, xcd+24}
    int bid = blockIdx.x;
    int xcd = bid & 7, j = bid >> 3;          // j in 0..111
    int brick = xcd + 8 * (j >> 5);
    if (brick >= NBRICK) return;              // dead pad blocks (launch last)
    int intra = j & 31;
    int bp = brick >> 2, bt = brick & 3;      // 7 x 4 brick grid
    int p = bp * 4 + (intra >> 3);            // 4 p-rows per brick
    int t = bt * 8 + (intra & 7);             // 8 t-cols per brick
    if (p >= NP || t >= NT) return;           // ragged brick edges
    size_t i0 = (size_t)p * 256, j0 = (size_t)t * 256;

    if (tid < 256) {
#pragma unroll
        for (int k = 0; k < 8; k++) { topv[tid][k] = 3.4e38f; topi[tid][k] = 0x7fffffff; }
    }

    f32x4 acc[4][8] = {};

    // staging role: tIdx 0..3 = Ahi,Alo,Bhi,Blo ; wsub = half
    int tIdx = wave >> 1, wsub = wave & 1;
    const _Float16* ssrc = (tIdx & 1) ? xlo : xhi;
    size_t srow = (tIdx < 2) ? i0 : j0;
    int toff = tIdx * 16384;

    char* buf0 = lds;
    char* buf1 = lds + 65536;

    __syncthreads();   // topv init visible
    stage32(buf0 + toff, ssrc, srow, 0, lane, wsub);

#pragma unroll 1
    for (int c = 0; c < 64; c++) {
        char* cur = (c & 1) ? buf1 : buf0;
        char* nxt = (c & 1) ? buf0 : buf1;
        if (c < 63) {
            stage32(nxt + toff, ssrc, srow, (c + 1) * 32, lane, wsub);
            asm volatile("s_waitcnt vmcnt(8)" ::: "memory");
        } else {
            asm volatile("s_waitcnt vmcnt(0)" ::: "memory");
        }
        __builtin_amdgcn_sched_barrier(0);
        __builtin_amdgcn_s_barrier();
        __builtin_amdgcn_sched_barrier(0);

        const char* Ah = cur;
        const char* Al = cur + 16384;
        const char* Bh = cur + 32768;
        const char* Bl = cur + 49152;
        half8 ah[4], al[4];
#pragma unroll
        for (int m = 0; m < 4; m++) ah[m] = frag_read32(Ah, wr * 64 + m * 16 + l15, lane);
#pragma unroll
        for (int m = 0; m < 4; m++) al[m] = frag_read32(Al, wr * 64 + m * 16 + l15, lane);
#pragma unroll
        for (int n = 0; n < 8; n++) {
            half8 bh = frag_read32(Bh, wc * 128 + n * 16 + l15, lane);
            half8 bl = frag_read32(Bl, wc * 128 + n * 16 + l15, lane);
#pragma unroll
            for (int m = 0; m < 4; m++)
                acc[m][n] = __builtin_amdgcn_mfma_f32_16x16x32_f16(ah[m], bh, acc[m][n], 0, 0, 0);
#pragma unroll
            for (int m = 0; m < 4; m++)
                acc[m][n] = __builtin_amdgcn_mfma_f32_16x16x32_f16(al[m], bh, acc[m][n], 0, 0, 0);
#pragma unroll
            for (int m = 0; m < 4; m++)
                acc[m][n] = __builtin_amdgcn_mfma_f32_16x16x32_f16(ah[m], bl, acc[m][n], 0, 0, 0);
        }
        __builtin_amdgcn_sched_barrier(0);
        __builtin_amdgcn_s_barrier();
    }

    // sq loads deferred so K-loop vmcnt counts only staging ops
    float sqi[4][4];
#pragma unroll
    for (int m = 0; m < 4; m++)
#pragma unroll
        for (int r = 0; r < 4; r++) {
            int gi = (int)i0 + wr * 64 + m * 16 + kg * 4 + r;
            sqi[m][r] = (gi < N_NODES) ? sq[gi] : 0.f;
        }
    float sqj[8];
#pragma unroll
    for (int n = 0; n < 8; n++) {
        int gj = (int)j0 + wc * 128 + n * 16 + l15;
        sqj[n] = (gj < N_NODES) ? sq[gj] : 0.f;
    }

    // ---- epilogue: d2 -> S (32-col chunks), per-row serial top-8 ----
    float* S = (float*)lds;   // [256][33]
#pragma unroll
    for (int cs = 0; cs < 8; cs++) {
        __syncthreads();
        if (wc == (cs >> 2)) {
            const int n0 = (cs & 3) * 2;
#pragma unroll
            for (int m = 0; m < 4; m++)
#pragma unroll
                for (int nn = 0; nn < 2; nn++)
#pragma unroll
                    for (int r = 0; r < 4; r++) {
                        int row = wr * 64 + m * 16 + kg * 4 + r;
                        float d2 = sqi[m][r] + sqj[n0 + nn] - 2.f * acc[m][n0 + nn][r];
                        S[row * 33 + nn * 16 + l15] = d2;
                    }
        }
        __syncthreads();
        if (tid < 256) {
            int r = tid, gi = (int)i0 + r;
            int cbase = (int)j0 + cs * 32;
#pragma unroll 4
            for (int jj = 0; jj < 32; jj++) {
                int gj = cbase + jj;
                if (gj >= N_NODES || gj == gi) continue;
                float v = S[r * 33 + jj];
                float wv = topv[r][7]; int wi = topi[r][7];
                if (v < wv || (v == wv && gj < wi)) {
                    int pos = 7;
                    while (pos > 0) {
                        float pv = topv[r][pos - 1]; int pi = topi[r][pos - 1];
                        if (v < pv || (v == pv && gj < pi)) {
                            topv[r][pos] = pv; topi[r][pos] = pi; pos--;
                        } else break;
                    }
                    topv[r][pos] = v; topi[r][pos] = gj;
                }
            }
        }
    }
    __syncthreads();
    if (tid < 256) {
        int gi = (int)i0 + tid;
        if (gi < N_NODES) {
#pragma unroll
            for (int k = 0; k < 8; k++) {
                candv[(size_t)gi * NSLOT + t * 8 + k] = topv[tid][k];
                candi[(size_t)gi * NSLOT + t * 8 + k] = topi[tid][k];
            }
        }
    }
}

// ------------- merge 25 sorted 8-lists -> knn[i][0..7] (lex (v,idx) order) -----
__global__ __launch_bounds__(256) void merge_topk_kernel(
        const float* __restrict__ candv, const int* __restrict__ candi,
        int* __restrict__ knn) {
    int i = blockIdx.x * 256 + threadIdx.x;
    if (i >= N_NODES) return;
    const float* cv = candv + (size_t)i * NSLOT;
    const int*   ci = candi + (size_t)i * NSLOT;
    float pv = -3.4e38f; int pi = -1;
    for (int k = 0; k < 8; k++) {
        float bv = 3.4e38f; int bi = 0x7fffffff;
        for (int m = 0; m < NSLOT; m++) {
            float v = cv[m]; int ix = ci[m];
            bool gt_prev = (v > pv) || (v == pv && ix > pi);
            bool lt_best = (v < bv) || (v == bv && ix < bi);
            if (gt_prev && lt_best) { bv = v; bi = ix; }
        }
        knn[(size_t)i * 8 + k] = bi;
        pv = bv; pi = bi;
    }
}

// ------------- graph build -------------
__global__ __launch_bounds__(256) void graph_init_kernel(int* deg, int* cnt) {
    int i = blockIdx.x * 256 + threadIdx.x;
    if (i < N_NODES) { deg[i] = 1; cnt[i] = 0; }
}
__global__ __launch_bounds__(256) void deg_count_kernel(const int* __restrict__ knn,
                                                        int* deg) {
    int e = blockIdx.x * 256 + threadIdx.x;
    if (e < N_NODES * 8) atomicAdd(&deg[knn[e]], 1);
}
__global__ __launch_bounds__(256) void dinv_kernel(const int* __restrict__ deg,
                                                   float* __restrict__ dinv) {
    int i = blockIdx.x * 256 + threadIdx.x;
    if (i < N_NODES) dinv[i] = rsqrtf((float)deg[i]);
}
__global__ __launch_bounds__(256) void scan_kernel(const int* __restrict__ deg,
                                                   int* __restrict__ row_ptr) {
    __shared__ int partial[256];
    const int CHUNK = (N_NODES + 255) / 256;
    int tid = threadIdx.x;
    int start = tid * CHUNK;
    int end = start + CHUNK; if (end > N_NODES) end = N_NODES;
    int s = 0;
    for (int i = start; i < end; i++) s += deg[i];
    partial[tid] = s;
    __syncthreads();
    if (tid == 0) {
        int run = 0;
        for (int k = 0; k < 256; k++) { int v = partial[k]; partial[k] = run; run += v; }
        row_ptr[N_NODES] = run;
    }
    __syncthreads();
    int run = partial[tid];
    for (int i = start; i < end; i++) { row_ptr[i] = run; run += deg[i]; }
}
__global__ __launch_bounds__(256) void scatter_kernel(const int* __restrict__ knn,
        const int* __restrict__ row_ptr, int* cnt, int* __restrict__ col) {
    int i = blockIdx.x * 256 + threadIdx.x;
    if (i >= N_NODES) return;
    int ptr = row_ptr[i] + atomicAdd(&cnt[i], 1);
    col[ptr] = i;                                   // self-loop
#pragma unroll
    for (int j = 0; j < 8; j++) {
        int d = knn[(size_t)i * 8 + j];
        int q = row_ptr[d] + atomicAdd(&cnt[d], 1);
        col[q] = i;
    }
}

// ------------- fp16 MFMA GEMM  C[M,N] = A[M,K] @ Bt[N,K]^T  (f32 out) --------
__global__ __launch_bounds__(256) void hgemm_nt_kernel(
        const _Float16* __restrict__ A, const _Float16* __restrict__ Bt,
        float* __restrict__ C, int M, int N, int K) {
    __shared__ char Alds[16384], Blds[16384];
    int tid = threadIdx.x, lane = tid & 63, wave = tid >> 6;
    int wr = wave >> 1, wc = wave & 1;
    int l15 = lane & 15, kg = lane >> 4;
    int nt = N >> 7;
    int i0 = (blockIdx.x / nt) * 128, j0 = (blockIdx.x % nt) * 128;
    f32x4 acc[4][4] = {};

#pragma unroll 1
    for (int kk = 0; kk < K; kk += 64) {
        __syncthreads();
#pragma unroll
        for (int g = 0; g < 4; g++) {
            int R = wave * 32 + g * 8;
            int swzk = ((lane & 7) ^ (lane >> 3)) << 3;
            const _Float16* ga = A + (size_t)(i0 + R + (lane >> 3)) * K + kk + swzk;
            gld_lds16(ga, Alds + R * 128);
            const _Float16* gb = Bt + (size_t)(j0 + R + (lane >> 3)) * K + kk + swzk;
            gld_lds16(gb, Blds + R * 128);
        }
        __syncthreads();
#pragma unroll
        for (int s = 0; s < 2; s++) {
            half8 a[4], b[4];
#pragma unroll
            for (int m = 0; m < 4; m++) a[m] = frag_read(Alds, wr * 64 + m * 16 + l15, s, lane);
#pragma unroll
            for (int n = 0; n < 4; n++) b[n] = frag_read(Blds, wc * 64 + n * 16 + l15, s, lane);
#pragma unroll
            for (int m = 0; m < 4; m++)
#pragma unroll
                for (int n = 0; n < 4; n++)
                    acc[m][n] = __builtin_amdgcn_mfma_f32_16x16x32_f16(a[m], b[n], acc[m][n], 0, 0, 0);
        }
    }
#pragma unroll
    for (int m = 0; m < 4; m++)
#pragma unroll
        for (int n = 0; n < 4; n++)
#pragma unroll
            for (int r = 0; r < 4; r++) {
                int row = i0 + wr * 64 + m * 16 + kg * 4 + r;
                int colj = j0 + wc * 64 + n * 16 + l15;
                C[(size_t)row * N + colj] = acc[m][n][r];
            }
}

// ------------- GCN aggregation: out[d] = relu(dinv[d]*sum hw[s]*dinv[s] + b) ---
template <bool HALF>
__global__ __launch_bounds__(256) void aggregate_kernel(
        const float* __restrict__ hw, const int* __restrict__ row_ptr,
        const int* __restrict__ col, const float* __restrict__ dinv,
        const float* __restrict__ bias, void* __restrict__ outp) {
    int node = blockIdx.x * 4 + (threadIdx.x >> 6);
    int lane = threadIdx.x & 63;
    int e0 = row_ptr[node], e1 = row_ptr[node + 1];
    float4 acc0 = {0.f, 0.f, 0.f, 0.f}, acc1 = {0.f, 0.f, 0.f, 0.f};
    for (int e = e0; e < e1; e++) {
        int s = col[e];
        float w = dinv[s];
        const float* hr = hw + (size_t)s * ODIM;
        float4 v0 = *(const float4*)(hr + lane * 4);
        float4 v1 = *(const float4*)(hr + 256 + lane * 4);
        acc0.x = fmaf(w, v0.x, acc0.x); acc0.y = fmaf(w, v0.y, acc0.y);
        acc0.z = fmaf(w, v0.z, acc0.z); acc0.w = fmaf(w, v0.w, acc0.w);
        acc1.x = fmaf(w, v1.x, acc1.x); acc1.y = fmaf(w, v1.y, acc1.y);
        acc1.z = fmaf(w, v1.z, acc1.z); acc1.w = fmaf(w, v1.w, acc1.w);
    }
    float wd = dinv[node];
    float4 b0 = *(const float4*)(bias + lane * 4);
    float4 b1 = *(const float4*)(bias + 256 + lane * 4);
    float o[8];
    o[0] = fmaxf(fmaf(acc0.x, wd, b0.x), 0.f);
    o[1] = fmaxf(fmaf(acc0.y, wd, b0.y), 0.f);
    o[2] = fmaxf(fmaf(acc0.z, wd, b0.z), 0.f);
    o[3] = fmaxf(fmaf(acc0.w, wd, b0.w), 0.f);
    o[4] = fmaxf(fmaf(acc1.x, wd, b1.x), 0.f);
    o[5] = fmaxf(fmaf(acc1.y, wd, b1.y), 0.f);
    o[6] = fmaxf(fmaf(acc1.z, wd, b1.z), 0.f);
    o[7] = fmaxf(fmaf(acc1.w, wd, b1.w), 0.f);
    if (HALF) {
        _Float16* out = (_Float16*)outp;
        half4 h0, h1;
#pragma unroll
        for (int j = 0; j < 4; j++) { h0[j] = (_Float16)o[j]; h1[j] = (_Float16)o[4 + j]; }
        *(half4*)(out + (size_t)node * ODIM + lane * 4)       = h0;
        *(half4*)(out + (size_t)node * ODIM + 256 + lane * 4) = h1;
    } else {
        float* out = (float*)outp;
        float4 f0 = {o[0], o[1], o[2], o[3]}, f1 = {o[4], o[5], o[6], o[7]};
        *(float4*)(out + (size_t)node * ODIM + lane * 4)       = f0;
        *(float4*)(out + (size_t)node * ODIM + 256 + lane * 4) = f1;
    }
}

extern "C" void kernel_launch(void* const* d_in, const int* in_sizes, int n_in,
                              void* d_out, int out_size, void* d_ws, size_t ws_size,
                              hipStream_t stream) {
    const float* x  = (const float*)d_in[0];
    const float* W1 = (const float*)d_in[1];
    const float* b1 = (const float*)d_in[2];
    const float* W2 = (const float*)d_in[3];
    const float* b2 = (const float*)d_in[4];
    float* out = (float*)d_out;
    char* ws = (char*)d_ws;

    _Float16* xhi  = (_Float16*)(ws + XHI_OFF);
    _Float16* xlo  = (_Float16*)(ws + XLO_OFF);
    float* candv   = (float*)(ws + CANDV_OFF);
    int*   candi   = (int*)  (ws + CANDI_OFF);
    float* sq      = (float*)(ws + SQ_OFF);
    int*   knn     = (int*)  (ws + KNN_OFF);
    int*   deg     = (int*)  (ws + DEG_OFF);
    int*   cnt     = (int*)  (ws + CNT_OFF);
    float* dinv    = (float*)(ws + DINV_OFF);
    int*   row_ptr = (int*)  (ws + RPTR_OFF);
    int*   col     = (int*)  (ws + COL_OFF);
    _Float16* w1t  = (_Float16*)(ws + W1T_OFF);
    _Float16* w2t  = (_Float16*)(ws + W2T_OFF);
    float* hw      = (float*)(ws + HW_OFF);       // reuses xlo region (post-gram)
    _Float16* h1h  = (_Float16*)(ws + H1H_OFF);   // reuses xlo region (post-gram)

    conv_split_kernel<<<12544, 256, 0, stream>>>(x, xhi, xlo);
    sq_kernel<<<N_NODES, 64, 0, stream>>>(x, sq);
    wtrans_kernel<<<dim3(CDIM / 64, ODIM / 64), 256, 0, stream>>>(W1, w1t, CDIM, ODIM);
    wtrans_kernel<<<dim3(ODIM / 64, ODIM / 64), 256, 0, stream>>>(W2, w2t, ODIM, ODIM);

    gram_topk_mfma<<<GRAM_GRID, 512, 0, stream>>>(xhi, xlo, sq, candv, candi);
    merge_topk_kernel<<<(N_NODES + 255) / 256, 256, 0, stream>>>(candv, candi, knn);

    graph_init_kernel<<<(N_NODES + 255) / 256, 256, 0, stream>>>(deg, cnt);
    deg_count_kernel<<<(N_NODES * 8) / 256, 256, 0, stream>>>(knn, deg);
    dinv_kernel<<<(N_NODES + 255) / 256, 256, 0, stream>>>(deg, dinv);
    scan_kernel<<<1, 256, 0, stream>>>(deg, row_ptr);
    scatter_kernel<<<(N_NODES + 255) / 256, 256, 0, stream>>>(knn, row_ptr, cnt, col);

    hgemm_nt_kernel<<<(N_NODES / 128) * (ODIM / 128), 256, 0, stream>>>(xhi, w1t, hw, N_NODES, ODIM, CDIM);
    aggregate_kernel<true><<<N_NODES / 4, 256, 0, stream>>>(hw, row_ptr, col, dinv, b1, (void*)h1h);
    hgemm_nt_kernel<<<(N_NODES / 128) * (ODIM / 128), 256, 0, stream>>>(h1h, w2t, hw, N_NODES, ODIM, ODIM);
    aggregate_kernel<false><<<N_NODES / 4, 256, 0, stream>>>(hw, row_ptr, col, dinv, b2, (void*)out);
}

// Round 7
// 1672.439 us; speedup vs baseline: 1.4299x; 1.4299x over previous
//
#include <hip/hip_runtime.h>

typedef __attribute__((ext_vector_type(8))) _Float16 half8;
typedef __attribute__((ext_vector_type(4))) _Float16 half4;
typedef __attribute__((ext_vector_type(4))) float f32x4;

#define N_NODES 6272
#define CDIM    2048
#define ODIM    512
#define NP      25      // 256-row panels (ceil 6272/256)
#define NT      25      // 256-col tiles
#define NTILE   625
#define NSLOT   200     // 25 tiles * 8 candidates per node

// ---------------- workspace layout (bytes) ----------------
#define XHI_OFF    0ul
#define XLO_OFF    25690112ul
#define CANDV_OFF  51380224ul
#define CANDI_OFF  56397824ul
#define SQ_OFF     61415424ul
#define KNN_OFF    61440512ul
#define DEG_OFF    61641216ul
#define CNT_OFF    61666304ul
#define DINV_OFF   61691392ul
#define RPTR_OFF   61716480ul
#define COL_OFF    61741824ul
#define W1T_OFF    61967616ul
#define W2T_OFF    64064768ul
// hw (f32, 12.8MB) and h1h (fp16, 6.4MB) reuse the XLO region after gram is done
#define HW_OFF     XLO_OFF
#define H1H_OFF    (XLO_OFF + 12845056ul)

// gram LDS tile offsets within one 64KB buffer
#define OFF_AH 0
#define OFF_AL 16384
#define OFF_BH 32768
#define OFF_BL 49152

// ---------------- async global->LDS (16B per lane, wave-uniform LDS base) ----
__device__ __forceinline__ void gld_lds16(const void* g, void* l) {
    __builtin_amdgcn_global_load_lds(
        (const __attribute__((address_space(1))) void*)g,
        (__attribute__((address_space(3))) void*)l, 16, 0, 0);
}

// ======== BK=64 helpers (hgemm) ========
__device__ __forceinline__ half8 frag_read(const char* base, int row, int s, int lane) {
    int b = (s * 4 + (lane >> 4)) ^ (row & 7);
    return *(const half8*)(base + row * 128 + b * 16);
}

// ======== BK=32 helpers (gram) ========
// tile layout [rows][32 f16 = 64B], 16B block q holds global k-block q ^ S(row),
// S(row) = (row&3) ^ ((row>>2)&3)
__device__ __forceinline__ half8 frag_read32(const char* tile, int row, int lane) {
    int b = ((lane >> 4) ^ (row & 3) ^ ((row >> 2) & 3)) & 3;
    return *(const half8*)(tile + row * 64 + b * 16);
}

// stage one 16-row segment (1KB) of a 256x32 f16 tile. R multiple of 16.
__device__ __forceinline__ void stage_seg(char* tile, const _Float16* src,
                                          size_t grow0, int kk, int R, int lane) {
    int r_in = lane >> 2;
    int kb = (lane & 3) ^ (r_in & 3) ^ ((r_in >> 2) & 3);
    const _Float16* gp = src + (grow0 + (size_t)(R + r_in)) * CDIM + kk + kb * 8;
    gld_lds16(gp, tile + R * 64);
}

#define MF(a, b, c) __builtin_amdgcn_mfma_f32_16x16x32_f16(a, b, c, 0, 0, 0)
// 12 MFMAs for one n-column: passes hi*hi, lo*hi, hi*lo (all indices compile-time)
#define MFMA_N(NN, BH, BL) do {                                                   \
    acc[0][NN] = MF(ah[0], BH, acc[0][NN]); acc[1][NN] = MF(ah[1], BH, acc[1][NN]); \
    acc[2][NN] = MF(ah[2], BH, acc[2][NN]); acc[3][NN] = MF(ah[3], BH, acc[3][NN]); \
    acc[0][NN] = MF(al[0], BH, acc[0][NN]); acc[1][NN] = MF(al[1], BH, acc[1][NN]); \
    acc[2][NN] = MF(al[2], BH, acc[2][NN]); acc[3][NN] = MF(al[3], BH, acc[3][NN]); \
    acc[0][NN] = MF(ah[0], BL, acc[0][NN]); acc[1][NN] = MF(ah[1], BL, acc[1][NN]); \
    acc[2][NN] = MF(ah[2], BL, acc[2][NN]); acc[3][NN] = MF(ah[3], BL, acc[3][NN]); \
} while (0)

// phases 1..3: read B frags for n=2P,2P+1; issue one staging part; barrier; MFMA.
#define PHASE(P, STILE, SSRC, SROW0) {                                            \
    half8 bh0 = frag_read32(cur + OFF_BH, wc * 128 + (2*(P))*16 + l15, lane);     \
    half8 bh1 = frag_read32(cur + OFF_BH, wc * 128 + (2*(P)+1)*16 + l15, lane);   \
    half8 bl0 = frag_read32(cur + OFF_BL, wc * 128 + (2*(P))*16 + l15, lane);     \
    half8 bl1 = frag_read32(cur + OFF_BL, wc * 128 + (2*(P)+1)*16 + l15, lane);   \
    if (pf) {                                                                     \
        stage_seg(nxt + STILE, SSRC, SROW0, kk2, wave * 32, lane);                \
        stage_seg(nxt + STILE, SSRC, SROW0, kk2, wave * 32 + 16, lane);           \
    }                                                                             \
    __builtin_amdgcn_s_barrier();                                                 \
    asm volatile("s_waitcnt lgkmcnt(0)" ::: "memory");                            \
    __builtin_amdgcn_sched_barrier(0);                                            \
    __builtin_amdgcn_s_setprio(1);                                                \
    MFMA_N(2*(P),   bh0, bl0);                                                    \
    MFMA_N(2*(P)+1, bh1, bl1);                                                    \
    __builtin_amdgcn_s_setprio(0);                                                \
    __builtin_amdgcn_s_barrier();                                                 \
}

// ---------------- x -> (hi, lo) fp16 split ----------------
__global__ __launch_bounds__(256) void conv_split_kernel(const float* __restrict__ x,
        _Float16* __restrict__ xhi, _Float16* __restrict__ xlo) {
    size_t idx = ((size_t)blockIdx.x * 256 + threadIdx.x) * 4;
    float4 v = *(const float4*)(x + idx);
    float vv[4] = {v.x, v.y, v.z, v.w};
    half4 h, l;
#pragma unroll
    for (int j = 0; j < 4; j++) {
        _Float16 hj = (_Float16)vv[j];
        h[j] = hj;
        l[j] = (_Float16)(vv[j] - (float)hj);
    }
    *(half4*)(xhi + idx) = h;
    *(half4*)(xlo + idx) = l;
}

// ---------------- W [K][N] f32 -> Wt [N][K] f16 ----------------
__global__ __launch_bounds__(256) void wtrans_kernel(const float* __restrict__ W,
        _Float16* __restrict__ Wt, int K, int N) {
    __shared__ float tile[64][65];
    int kb = blockIdx.x * 64, nb = blockIdx.y * 64;
    int tid = threadIdx.x;
    int r = tid >> 2, c0 = (tid & 3) * 16;
#pragma unroll
    for (int u = 0; u < 4; u++) {
        float4 v = *(const float4*)(W + (size_t)(kb + r) * N + nb + c0 + u * 4);
        tile[r][c0 + u * 4 + 0] = v.x; tile[r][c0 + u * 4 + 1] = v.y;
        tile[r][c0 + u * 4 + 2] = v.z; tile[r][c0 + u * 4 + 3] = v.w;
    }
    __syncthreads();
    int rn = tid >> 2, ck0 = (tid & 3) * 16;
#pragma unroll
    for (int u = 0; u < 4; u++) {
        half4 o;
#pragma unroll
        for (int j = 0; j < 4; j++) o[j] = (_Float16)tile[ck0 + u * 4 + j][rn];
        *(half4*)(Wt + (size_t)(nb + rn) * K + kb + ck0 + u * 4) = o;
    }
}

// ---------------- sq[i] = sum_c x[i][c]^2 (fp32, exact vs ref) ----------------
__global__ __launch_bounds__(64) void sq_kernel(const float* __restrict__ x,
                                                float* __restrict__ sq) {
    int i = blockIdx.x;
    int t = threadIdx.x;
    const float* row = x + (size_t)i * CDIM;
    float s = 0.f;
#pragma unroll
    for (int k = 0; k < CDIM / 256; k++) {
        float4 v = *(const float4*)(row + (k * 64 + t) * 4);
        s += v.x * v.x + v.y * v.y + v.z * v.z + v.w * v.w;
    }
#pragma unroll
    for (int off = 32; off; off >>= 1) s += __shfl_down(s, off, 64);
    if (t == 0) sq[i] = s;
}

// ---------- fused MFMA Gram (256x256 tiles) + row top-8 — 4-phase schedule ----------
// dot = hi.hi + hi.lo + lo.hi ; grid = 625, 512 threads (8 waves, wr=wave>>1, wc=wave&1).
// Per K-step (BK=32): 4 phases x {4 B-frag ds_reads || 2 staging gld_lds -> barrier ->
// lgkmcnt(0) -> setprio -> 24 MFMA -> setprio -> barrier}; phase 0 also reads A frags
// and does the single COUNTED vmcnt(2) per step (never drains the prefetch pipe).
// All acc[][] indices compile-time (rule #20).
__global__ __launch_bounds__(512, 2) void gram_topk_mfma(
        const _Float16* __restrict__ xhi, const _Float16* __restrict__ xlo,
        const float* __restrict__ sq,
        float* __restrict__ candv, int* __restrict__ candi) {
    __shared__ char lds[131072];       // 2 bufs x {Ahi,Alo,Bhi,Blo} x 16KB; S unions
    __shared__ float topv[256][9];
    __shared__ int   topi[256][9];

    int tid = threadIdx.x, lane = tid & 63, wave = tid >> 6;
    int wr = wave >> 1, wc = wave & 1;
    int l15 = lane & 15, kg = lane >> 4;

    // bijective XCD swizzle over 625 = 8*78 + 1
    int bid = blockIdx.x;
    int xcd = bid & 7, loc = bid >> 3;
    int swz = (xcd < 1) ? loc : (79 + (xcd - 1) * 78 + loc);
    int p = swz / NT, t = swz % NT;
    size_t i0 = (size_t)p * 256, j0 = (size_t)t * 256;

    if (tid < 256) {
#pragma unroll
        for (int k = 0; k < 8; k++) { topv[tid][k] = 3.4e38f; topi[tid][k] = 0x7fffffff; }
    }
    __syncthreads();   // before prologue staging (syncthreads drains vmcnt -> do it now)

    f32x4 acc[4][8] = {};
    char* buf0 = lds;
    char* buf1 = lds + 65536;

    // prologue: stage all 4 parts of chunk 0 (8 gld_lds/wave)
    stage_seg(buf0 + OFF_AH, xhi, i0, 0, wave * 32, lane);
    stage_seg(buf0 + OFF_AH, xhi, i0, 0, wave * 32 + 16, lane);
    stage_seg(buf0 + OFF_AL, xlo, i0, 0, wave * 32, lane);
    stage_seg(buf0 + OFF_AL, xlo, i0, 0, wave * 32 + 16, lane);
    stage_seg(buf0 + OFF_BH, xhi, j0, 0, wave * 32, lane);
    stage_seg(buf0 + OFF_BH, xhi, j0, 0, wave * 32 + 16, lane);
    stage_seg(buf0 + OFF_BL, xlo, j0, 0, wave * 32, lane);
    stage_seg(buf0 + OFF_BL, xlo, j0, 0, wave * 32 + 16, lane);

#pragma unroll 1
    for (int c = 0; c < 64; c++) {
        char* cur = (c & 1) ? buf1 : buf0;
        char* nxt = (c & 1) ? buf0 : buf1;
        const int kk2 = (c + 1) * 32;
        const bool pf = (c < 63);
        half8 ah[4], al[4];

        // ---------- phase 0: stage Ahi(c+1); counted vmcnt; A frags + B n=0,1 ----------
        if (pf) {
            stage_seg(nxt + OFF_AH, xhi, i0, kk2, wave * 32, lane);
            stage_seg(nxt + OFF_AH, xhi, i0, kk2, wave * 32 + 16, lane);
            asm volatile("s_waitcnt vmcnt(2)" ::: "memory");
        } else {
            asm volatile("s_waitcnt vmcnt(0)" ::: "memory");
        }
        __builtin_amdgcn_sched_barrier(0);
        __builtin_amdgcn_s_barrier();
        __builtin_amdgcn_sched_barrier(0);
        {
#pragma unroll
            for (int m = 0; m < 4; m++) ah[m] = frag_read32(cur + OFF_AH, wr * 64 + m * 16 + l15, lane);
#pragma unroll
            for (int m = 0; m < 4; m++) al[m] = frag_read32(cur + OFF_AL, wr * 64 + m * 16 + l15, lane);
            half8 bh0 = frag_read32(cur + OFF_BH, wc * 128 + 0  + l15, lane);
            half8 bh1 = frag_read32(cur + OFF_BH, wc * 128 + 16 + l15, lane);
            half8 bl0 = frag_read32(cur + OFF_BL, wc * 128 + 0  + l15, lane);
            half8 bl1 = frag_read32(cur + OFF_BL, wc * 128 + 16 + l15, lane);
            asm volatile("s_waitcnt lgkmcnt(0)" ::: "memory");
            __builtin_amdgcn_sched_barrier(0);
            __builtin_amdgcn_s_setprio(1);
            MFMA_N(0, bh0, bl0);
            MFMA_N(1, bh1, bl1);
            __builtin_amdgcn_s_setprio(0);
            __builtin_amdgcn_s_barrier();
        }
        // ---------- phases 1-3 ----------
        PHASE(1, OFF_AL, xlo, i0);
        PHASE(2, OFF_BH, xhi, j0);
        PHASE(3, OFF_BL, xlo, j0);
    }

    // sq loads deferred so K-loop vmcnt counts only staging ops
    float sqi[4][4];
#pragma unroll
    for (int m = 0; m < 4; m++)
#pragma unroll
        for (int r = 0; r < 4; r++) {
            int gi = (int)i0 + wr * 64 + m * 16 + kg * 4 + r;
            sqi[m][r] = (gi < N_NODES) ? sq[gi] : 0.f;
        }
    float sqj[8];
#pragma unroll
    for (int n = 0; n < 8; n++) {
        int gj = (int)j0 + wc * 128 + n * 16 + l15;
        sqj[n] = (gj < N_NODES) ? sq[gj] : 0.f;
    }

    // ---- epilogue: d2 -> S (32-col chunks), per-row serial top-8 ----
    float* S = (float*)lds;   // [256][33]
#pragma unroll
    for (int cs = 0; cs < 8; cs++) {
        __syncthreads();
        if (wc == (cs >> 2)) {
            const int n0 = (cs & 3) * 2;
#pragma unroll
            for (int m = 0; m < 4; m++)
#pragma unroll
                for (int nn = 0; nn < 2; nn++)
#pragma unroll
                    for (int r = 0; r < 4; r++) {
                        int row = wr * 64 + m * 16 + kg * 4 + r;
                        float d2 = sqi[m][r] + sqj[n0 + nn] - 2.f * acc[m][n0 + nn][r];
                        S[row * 33 + nn * 16 + l15] = d2;
                    }
        }
        __syncthreads();
        if (tid < 256) {
            int r = tid, gi = (int)i0 + r;
            int cbase = (int)j0 + cs * 32;
#pragma unroll 4
            for (int jj = 0; jj < 32; jj++) {
                int gj = cbase + jj;
                if (gj >= N_NODES || gj == gi) continue;
                float v = S[r * 33 + jj];
                float wv = topv[r][7]; int wi = topi[r][7];
                if (v < wv || (v == wv && gj < wi)) {
                    int pos = 7;
                    while (pos > 0) {
                        float pv = topv[r][pos - 1]; int pi = topi[r][pos - 1];
                        if (v < pv || (v == pv && gj < pi)) {
                            topv[r][pos] = pv; topi[r][pos] = pi; pos--;
                        } else break;
                    }
                    topv[r][pos] = v; topi[r][pos] = gj;
                }
            }
        }
    }
    __syncthreads();
    if (tid < 256) {
        int gi = (int)i0 + tid;
        if (gi < N_NODES) {
#pragma unroll
            for (int k = 0; k < 8; k++) {
                candv[(size_t)gi * NSLOT + t * 8 + k] = topv[tid][k];
                candi[(size_t)gi * NSLOT + t * 8 + k] = topi[tid][k];
            }
        }
    }
}

// ------------- merge 25 sorted 8-lists -> knn (wave per node, lex (v,idx)) -----
__global__ __launch_bounds__(256) void merge_topk_kernel(
        const float* __restrict__ candv, const int* __restrict__ candi,
        int* __restrict__ knn) {
    int node = blockIdx.x * 4 + (threadIdx.x >> 6);
    int lane = threadIdx.x & 63;
    const float* cv = candv + (size_t)node * NSLOT;
    const int*   ci = candi + (size_t)node * NSLOT;
    float v[4]; int ix[4];
#pragma unroll
    for (int u = 0; u < 4; u++) {
        int s = u * 64 + lane;
        bool ok = (s < NSLOT);
        v[u]  = ok ? cv[s] : 3.4e38f;
        ix[u] = ok ? ci[s] : 0x7fffffff;
    }
#pragma unroll 1
    for (int k = 0; k < 8; k++) {
        float bv = v[0]; int bi = ix[0];
#pragma unroll
        for (int u = 1; u < 4; u++)
            if (v[u] < bv || (v[u] == bv && ix[u] < bi)) { bv = v[u]; bi = ix[u]; }
#pragma unroll
        for (int off = 32; off; off >>= 1) {
            float ov = __shfl_xor(bv, off, 64);
            int   oi = __shfl_xor(bi, off, 64);
            if (ov < bv || (ov == bv && oi < bi)) { bv = ov; bi = oi; }
        }
        if (lane == 0) knn[(size_t)node * 8 + k] = bi;
#pragma unroll
        for (int u = 0; u < 4; u++)
            if (ix[u] == bi) { v[u] = 3.4e38f; ix[u] = 0x7fffffff; }
    }
}

// ------------- graph build -------------
__global__ __launch_bounds__(256) void graph_init_kernel(int* deg, int* cnt) {
    int i = blockIdx.x * 256 + threadIdx.x;
    if (i < N_NODES) { deg[i] = 1; cnt[i] = 0; }
}
__global__ __launch_bounds__(256) void deg_count_kernel(const int* __restrict__ knn,
                                                        int* deg) {
    int e = blockIdx.x * 256 + threadIdx.x;
    if (e < N_NODES * 8) atomicAdd(&deg[knn[e]], 1);
}
__global__ __launch_bounds__(256) void dinv_kernel(const int* __restrict__ deg,
                                                   float* __restrict__ dinv) {
    int i = blockIdx.x * 256 + threadIdx.x;
    if (i < N_NODES) dinv[i] = rsqrtf((float)deg[i]);
}
__global__ __launch_bounds__(256) void scan_kernel(const int* __restrict__ deg,
                                                   int* __restrict__ row_ptr) {
    __shared__ int partial[256];
    const int CHUNK = (N_NODES + 255) / 256;
    int tid = threadIdx.x;
    int start = tid * CHUNK;
    int end = start + CHUNK; if (end > N_NODES) end = N_NODES;
    int s = 0;
    for (int i = start; i < end; i++) s += deg[i];
    partial[tid] = s;
    __syncthreads();
    if (tid == 0) {
        int run = 0;
        for (int k = 0; k < 256; k++) { int v = partial[k]; partial[k] = run; run += v; }
        row_ptr[N_NODES] = run;
    }
    __syncthreads();
    int run = partial[tid];
    for (int i = start; i < end; i++) { row_ptr[i] = run; run += deg[i]; }
}
__global__ __launch_bounds__(256) void scatter_kernel(const int* __restrict__ knn,
        const int* __restrict__ row_ptr, int* cnt, int* __restrict__ col) {
    int i = blockIdx.x * 256 + threadIdx.x;
    if (i >= N_NODES) return;
    int ptr = row_ptr[i] + atomicAdd(&cnt[i], 1);
    col[ptr] = i;                                   // self-loop
#pragma unroll
    for (int j = 0; j < 8; j++) {
        int d = knn[(size_t)i * 8 + j];
        int q = row_ptr[d] + atomicAdd(&cnt[d], 1);
        col[q] = i;
    }
}

// ------------- fp16 MFMA GEMM  C[M,N] = A[M,K] @ Bt[N,K]^T  (f32 out) --------
__global__ __launch_bounds__(256) void hgemm_nt_kernel(
        const _Float16* __restrict__ A, const _Float16* __restrict__ Bt,
        float* __restrict__ C, int M, int N, int K) {
    __shared__ char Alds[16384], Blds[16384];
    int tid = threadIdx.x, lane = tid & 63, wave = tid >> 6;
    int wr = wave >> 1, wc = wave & 1;
    int l15 = lane & 15, kg = lane >> 4;
    int nt = N >> 7;
    int i0 = (blockIdx.x / nt) * 128, j0 = (blockIdx.x % nt) * 128;
    f32x4 acc[4][4] = {};

#pragma unroll 1
    for (int kk = 0; kk < K; kk += 64) {
        __syncthreads();
#pragma unroll
        for (int g = 0; g < 4; g++) {
            int R = wave * 32 + g * 8;
            int swzk = ((lane & 7) ^ (lane >> 3)) << 3;
            const _Float16* ga = A + (size_t)(i0 + R + (lane >> 3)) * K + kk + swzk;
            gld_lds16(ga, Alds + R * 128);
            const _Float16* gb = Bt + (size_t)(j0 + R + (lane >> 3)) * K + kk + swzk;
            gld_lds16(gb, Blds + R * 128);
        }
        __syncthreads();
#pragma unroll
        for (int s = 0; s < 2; s++) {
            half8 a[4], b[4];
#pragma unroll
            for (int m = 0; m < 4; m++) a[m] = frag_read(Alds, wr * 64 + m * 16 + l15, s, lane);
#pragma unroll
            for (int n = 0; n < 4; n++) b[n] = frag_read(Blds, wc * 64 + n * 16 + l15, s, lane);
#pragma unroll
            for (int m = 0; m < 4; m++)
#pragma unroll
                for (int n = 0; n < 4; n++)
                    acc[m][n] = __builtin_amdgcn_mfma_f32_16x16x32_f16(a[m], b[n], acc[m][n], 0, 0, 0);
        }
    }
#pragma unroll
    for (int m = 0; m < 4; m++)
#pragma unroll
        for (int n = 0; n < 4; n++)
#pragma unroll
            for (int r = 0; r < 4; r++) {
                int row = i0 + wr * 64 + m * 16 + kg * 4 + r;
                int colj = j0 + wc * 64 + n * 16 + l15;
                C[(size_t)row * N + colj] = acc[m][n][r];
            }
}

// ------------- GCN aggregation: out[d] = relu(dinv[d]*sum hw[s]*dinv[s] + b) ---
template <bool HALF>
__global__ __launch_bounds__(256) void aggregate_kernel(
        const float* __restrict__ hw, const int* __restrict__ row_ptr,
        const int* __restrict__ col, const float* __restrict__ dinv,
        const float* __restrict__ bias, void* __restrict__ outp) {
    int node = blockIdx.x * 4 + (threadIdx.x >> 6);
    int lane = threadIdx.x & 63;
    int e0 = row_ptr[node], e1 = row_ptr[node + 1];
    float4 acc0 = {0.f, 0.f, 0.f, 0.f}, acc1 = {0.f, 0.f, 0.f, 0.f};
    for (int e = e0; e < e1; e++) {
        int s = col[e];
        float w = dinv[s];
        const float* hr = hw + (size_t)s * ODIM;
        float4 v0 = *(const float4*)(hr + lane * 4);
        float4 v1 = *(const float4*)(hr + 256 + lane * 4);
        acc0.x = fmaf(w, v0.x, acc0.x); acc0.y = fmaf(w, v0.y, acc0.y);
        acc0.z = fmaf(w, v0.z, acc0.z); acc0.w = fmaf(w, v0.w, acc0.w);
        acc1.x = fmaf(w, v1.x, acc1.x); acc1.y = fmaf(w, v1.y, acc1.y);
        acc1.z = fmaf(w, v1.z, acc1.z); acc1.w = fmaf(w, v1.w, acc1.w);
    }
    float wd = dinv[node];
    float4 b0 = *(const float4*)(bias + lane * 4);
    float4 b1 = *(const float4*)(bias + 256 + lane * 4);
    float o[8];
    o[0] = fmaxf(fmaf(acc0.x, wd, b0.x), 0.f);
    o[1] = fmaxf(fmaf(acc0.y, wd, b0.y), 0.f);
    o[2] = fmaxf(fmaf(acc0.z, wd, b0.z), 0.f);
    o[3] = fmaxf(fmaf(acc0.w, wd, b0.w), 0.f);
    o[4] = fmaxf(fmaf(acc1.x, wd, b1.x), 0.f);
    o[5] = fmaxf(fmaf(acc1.y, wd, b1.y), 0.f);
    o[6] = fmaxf(fmaf(acc1.z, wd, b1.z), 0.f);
    o[7] = fmaxf(fmaf(acc1.w, wd, b1.w), 0.f);
    if (HALF) {
        _Float16* out = (_Float16*)outp;
        half4 h0, h1;
#pragma unroll
        for (int j = 0; j < 4; j++) { h0[j] = (_Float16)o[j]; h1[j] = (_Float16)o[4 + j]; }
        *(half4*)(out + (size_t)node * ODIM + lane * 4)       = h0;
        *(half4*)(out + (size_t)node * ODIM + 256 + lane * 4) = h1;
    } else {
        float* out = (float*)outp;
        float4 f0 = {o[0], o[1], o[2], o[3]}, f1 = {o[4], o[5], o[6], o[7]};
        *(float4*)(out + (size_t)node * ODIM + lane * 4)       = f0;
        *(float4*)(out + (size_t)node * ODIM + 256 + lane * 4) = f1;
    }
}

extern "C" void kernel_launch(void* const* d_in, const int* in_sizes, int n_in,
                              void* d_out, int out_size, void* d_ws, size_t ws_size,
                              hipStream_t stream) {
    const float* x  = (const float*)d_in[0];
    const float* W1 = (const float*)d_in[1];
    const float* b1 = (const float*)d_in[2];
    const float* W2 = (const float*)d_in[3];
    const float* b2 = (const float*)d_in[4];
    float* out = (float*)d_out;
    char* ws = (char*)d_ws;

    _Float16* xhi  = (_Float16*)(ws + XHI_OFF);
    _Float16* xlo  = (_Float16*)(ws + XLO_OFF);
    float* candv   = (float*)(ws + CANDV_OFF);
    int*   candi   = (int*)  (ws + CANDI_OFF);
    float* sq      = (float*)(ws + SQ_OFF);
    int*   knn     = (int*)  (ws + KNN_OFF);
    int*   deg     = (int*)  (ws + DEG_OFF);
    int*   cnt     = (int*)  (ws + CNT_OFF);
    float* dinv    = (float*)(ws + DINV_OFF);
    int*   row_ptr = (int*)  (ws + RPTR_OFF);
    int*   col     = (int*)  (ws + COL_OFF);
    _Float16* w1t  = (_Float16*)(ws + W1T_OFF);
    _Float16* w2t  = (_Float16*)(ws + W2T_OFF);
    float* hw      = (float*)(ws + HW_OFF);       // reuses xlo region (post-gram)
    _Float16* h1h  = (_Float16*)(ws + H1H_OFF);   // reuses xlo region (post-gram)

    conv_split_kernel<<<12544, 256, 0, stream>>>(x, xhi, xlo);
    sq_kernel<<<N_NODES, 64, 0, stream>>>(x, sq);
    wtrans_kernel<<<dim3(CDIM / 64, ODIM / 64), 256, 0, stream>>>(W1, w1t, CDIM, ODIM);
    wtrans_kernel<<<dim3(ODIM / 64, ODIM / 64), 256, 0, stream>>>(W2, w2t, ODIM, ODIM);

    gram_topk_mfma<<<NTILE, 512, 0, stream>>>(xhi, xlo, sq, candv, candi);
    merge_topk_kernel<<<N_NODES / 4, 256, 0, stream>>>(candv, candi, knn);

    graph_init_kernel<<<(N_NODES + 255) / 256, 256, 0, stream>>>(deg, cnt);
    deg_count_kernel<<<(N_NODES * 8) / 256, 256, 0, stream>>>(knn, deg);
    dinv_kernel<<<(N_NODES + 255) / 256, 256, 0, stream>>>(deg, dinv);
    scan_kernel<<<1, 256, 0, stream>>>(deg, row_ptr);
    scatter_kernel<<<(N_NODES + 255) / 256, 256, 0, stream>>>(knn, row_ptr, cnt, col);

    hgemm_nt_kernel<<<(N_NODES / 128) * (ODIM / 128), 256, 0, stream>>>(xhi, w1t, hw, N_NODES, ODIM, CDIM);
    aggregate_kernel<true><<<N_NODES / 4, 256, 0, stream>>>(hw, row_ptr, col, dinv, b1, (void*)h1h);
    hgemm_nt_kernel<<<(N_NODES / 128) * (ODIM / 128), 256, 0, stream>>>(h1h, w2t, hw, N_NODES, ODIM, ODIM);
    aggregate_kernel<false><<<N_NODES / 4, 256, 0, stream>>>(hw, row_ptr, col, dinv, b2, (void*)out);
}

// Round 8
// 1668.101 us; speedup vs baseline: 1.4336x; 1.0026x over previous
//
#include <hip/hip_runtime.h>

typedef __attribute__((ext_vector_type(8))) _Float16 half8;
typedef __attribute__((ext_vector_type(4))) _Float16 half4;
typedef __attribute__((ext_vector_type(4))) float f32x4;

#define N_NODES 6272
#define CDIM    2048
#define ODIM    512
#define NT      25       // 256-col tiles (cand layout unchanged)
#define NSLOT   200      // 25 tiles * 8 candidates per node

// gram geometry: 128x256 tiles, 2 blocks/CU
#define TMG     128
#define NPG     49       // 6272/128 exactly
#define GRID_G  1225     // 49*25

// ---------------- workspace layout (bytes) ----------------
#define XHI_OFF    0ul
#define XLO_OFF    25690112ul
#define CANDV_OFF  51380224ul
#define CANDI_OFF  56397824ul
#define SQ_OFF     61415424ul
#define KNN_OFF    61440512ul
#define DEG_OFF    61641216ul
#define CNT_OFF    61666304ul
#define DINV_OFF   61691392ul
#define RPTR_OFF   61716480ul
#define COL_OFF    61741824ul
#define W1T_OFF    61967616ul
#define W2T_OFF    64064768ul
// hw (f32, 12.8MB) and h1h (fp16, 6.4MB) reuse the XLO region after gram is done
#define HW_OFF     XLO_OFF
#define H1H_OFF    (XLO_OFF + 12845056ul)

// gram LDS tile offsets (single 48KB buffer)
#define GAH 0        // Ahi 128x32 f16 = 8KB
#define GAL 8192     // Alo 8KB
#define GBH 16384    // Bhi 256x32 f16 = 16KB
#define GBL 32768    // Blo 16KB

// ---------------- async global->LDS (16B per lane, wave-uniform LDS base) ----
__device__ __forceinline__ void gld_lds16(const void* g, void* l) {
    __builtin_amdgcn_global_load_lds(
        (const __attribute__((address_space(1))) void*)g,
        (__attribute__((address_space(3))) void*)l, 16, 0, 0);
}

// ======== BK=64 helpers (hgemm) ========
__device__ __forceinline__ half8 frag_read(const char* base, int row, int s, int lane) {
    int b = (s * 4 + (lane >> 4)) ^ (row & 7);
    return *(const half8*)(base + row * 128 + b * 16);
}

// ======== BK=32 helpers (gram) ========
// tile layout [rows][32 f16 = 64B], 16B slot b holds global k-block b ^ S(row),
// S(row) = (row&3) ^ ((row>>2)&3)
__device__ __forceinline__ half8 frag_read32(const char* tile, int row, int lane) {
    int b = ((lane >> 4) ^ (row & 3) ^ ((row >> 2) & 3)) & 3;
    return *(const half8*)(tile + row * 64 + b * 16);
}

// stage one 16-row segment (1KB). LDS linear; global source pre-swizzled.
__device__ __forceinline__ void stage_seg(char* tile, const _Float16* src,
                                          size_t grow0, int kk, int R, int lane) {
    int r_in = lane >> 2;
    int kb = (lane & 3) ^ (r_in & 3) ^ ((r_in >> 2) & 3);
    const _Float16* gp = src + (grow0 + (size_t)(R + r_in)) * CDIM + kk + kb * 8;
    gld_lds16(gp, tile + R * 64);
}

// stage the whole 48KB step buffer: 48 segs, 6 per wave (uniform branches)
__device__ __forceinline__ void stage_all(char* lds, const _Float16* xhi,
        const _Float16* xlo, size_t i0, size_t j0, int kk, int wave, int lane) {
#pragma unroll
    for (int g = 0; g < 6; g++) {
        int s = wave * 6 + g;
        const _Float16* src; size_t base; char* tile; int r0;
        if (s < 8)       { src = xhi; base = i0; tile = lds + GAH; r0 = s * 16; }
        else if (s < 16) { src = xlo; base = i0; tile = lds + GAL; r0 = (s - 8) * 16; }
        else if (s < 32) { src = xhi; base = j0; tile = lds + GBH; r0 = (s - 16) * 16; }
        else             { src = xlo; base = j0; tile = lds + GBL; r0 = (s - 32) * 16; }
        stage_seg(tile, src, base, kk, r0, lane);
    }
}

#define MF(a, b, c) __builtin_amdgcn_mfma_f32_16x16x32_f16(a, b, c, 0, 0, 0)

// ---------------- x -> (hi, lo) fp16 split ----------------
__global__ __launch_bounds__(256) void conv_split_kernel(const float* __restrict__ x,
        _Float16* __restrict__ xhi, _Float16* __restrict__ xlo) {
    size_t idx = ((size_t)blockIdx.x * 256 + threadIdx.x) * 4;
    float4 v = *(const float4*)(x + idx);
    float vv[4] = {v.x, v.y, v.z, v.w};
    half4 h, l;
#pragma unroll
    for (int j = 0; j < 4; j++) {
        _Float16 hj = (_Float16)vv[j];
        h[j] = hj;
        l[j] = (_Float16)(vv[j] - (float)hj);
    }
    *(half4*)(xhi + idx) = h;
    *(half4*)(xlo + idx) = l;
}

// ---------------- W [K][N] f32 -> Wt [N][K] f16 ----------------
__global__ __launch_bounds__(256) void wtrans_kernel(const float* __restrict__ W,
        _Float16* __restrict__ Wt, int K, int N) {
    __shared__ float tile[64][65];
    int kb = blockIdx.x * 64, nb = blockIdx.y * 64;
    int tid = threadIdx.x;
    int r = tid >> 2, c0 = (tid & 3) * 16;
#pragma unroll
    for (int u = 0; u < 4; u++) {
        float4 v = *(const float4*)(W + (size_t)(kb + r) * N + nb + c0 + u * 4);
        tile[r][c0 + u * 4 + 0] = v.x; tile[r][c0 + u * 4 + 1] = v.y;
        tile[r][c0 + u * 4 + 2] = v.z; tile[r][c0 + u * 4 + 3] = v.w;
    }
    __syncthreads();
    int rn = tid >> 2, ck0 = (tid & 3) * 16;
#pragma unroll
    for (int u = 0; u < 4; u++) {
        half4 o;
#pragma unroll
        for (int j = 0; j < 4; j++) o[j] = (_Float16)tile[ck0 + u * 4 + j][rn];
        *(half4*)(Wt + (size_t)(nb + rn) * K + kb + ck0 + u * 4) = o;
    }
}

// ---------------- sq[i] = sum_c x[i][c]^2 (fp32, exact vs ref) ----------------
__global__ __launch_bounds__(64) void sq_kernel(const float* __restrict__ x,
                                                float* __restrict__ sq) {
    int i = blockIdx.x;
    int t = threadIdx.x;
    const float* row = x + (size_t)i * CDIM;
    float s = 0.f;
#pragma unroll
    for (int k = 0; k < CDIM / 256; k++) {
        float4 v = *(const float4*)(row + (k * 64 + t) * 4);
        s += v.x * v.x + v.y * v.y + v.z * v.z + v.w * v.w;
    }
#pragma unroll
    for (int off = 32; off; off >>= 1) s += __shfl_down(s, off, 64);
    if (t == 0) sq[i] = s;
}

// ---------- fused MFMA Gram (128x256 tiles, 2 blocks/CU) + row top-8 ----------
// dot = hi.hi + hi.lo + lo.hi ; grid = 1225, 512 threads (8 waves: wr=wave>>2 in
// 0..1, wc=wave&3 in 0..3; each wave owns a 64x64 sub-tile, acc[4][4] = 64 VGPR).
// Single-buffered BK=32; latency hidden by the SIBLING block on the CU (56KB LDS,
// <=128 VGPR via launch_bounds(512,4) -> 2 blocks / 16 waves per CU).
// All acc[][] indices compile-time (rule #20).
__global__ __launch_bounds__(512, 4) void gram_topk_mfma(
        const _Float16* __restrict__ xhi, const _Float16* __restrict__ xlo,
        const float* __restrict__ sq,
        float* __restrict__ candv, int* __restrict__ candi) {
    __shared__ char lds[49152];               // staging buffer; S overlays it
    __shared__ float topv[TMG][9];
    __shared__ unsigned short topi[TMG][10];

    int tid = threadIdx.x, lane = tid & 63, wave = tid >> 6;
    int wr = wave >> 2, wc = wave & 3;
    int l15 = lane & 15, kg = lane >> 4;

    // bijective XCD-chunked swizzle over 1225 = 8*153 + 1
    int bid = blockIdx.x;
    int xcd = bid & 7, loc = bid >> 3;
    int swz = (xcd < 1) ? loc : (154 + (xcd - 1) * 153 + loc);
    int p = swz / NT, t = swz % NT;
    size_t i0 = (size_t)p * TMG, j0 = (size_t)t * 256;

    if (tid < TMG) {
#pragma unroll
        for (int k = 0; k < 8; k++) { topv[tid][k] = 3.4e38f; topi[tid][k] = 0xFFFF; }
    }
    __syncthreads();

    f32x4 acc[4][4] = {};

#pragma unroll 1
    for (int c = 0; c < 64; c++) {
        stage_all(lds, xhi, xlo, i0, j0, c * 32, wave, lane);
        __syncthreads();                       // drains vmcnt -> staging visible
        half8 a[4];
        // pass 1 & 2: A-hi x {B-hi, B-lo}
#pragma unroll
        for (int m = 0; m < 4; m++) a[m] = frag_read32(lds + GAH, wr * 64 + m * 16 + l15, lane);
#pragma unroll
        for (int n = 0; n < 4; n++) {
            half8 bh = frag_read32(lds + GBH, wc * 64 + n * 16 + l15, lane);
            half8 bl = frag_read32(lds + GBL, wc * 64 + n * 16 + l15, lane);
#pragma unroll
            for (int m = 0; m < 4; m++) acc[m][n] = MF(a[m], bh, acc[m][n]);
#pragma unroll
            for (int m = 0; m < 4; m++) acc[m][n] = MF(a[m], bl, acc[m][n]);
        }
        // pass 3: A-lo x B-hi (reuse a[] registers)
#pragma unroll
        for (int m = 0; m < 4; m++) a[m] = frag_read32(lds + GAL, wr * 64 + m * 16 + l15, lane);
#pragma unroll
        for (int n = 0; n < 4; n++) {
            half8 bh = frag_read32(lds + GBH, wc * 64 + n * 16 + l15, lane);
#pragma unroll
            for (int m = 0; m < 4; m++) acc[m][n] = MF(a[m], bh, acc[m][n]);
        }
        __syncthreads();                       // LDS reusable for next stage
    }

    // sq values (deferred; outside the K-loop)
    float sqi[4][4];
#pragma unroll
    for (int m = 0; m < 4; m++)
#pragma unroll
        for (int r = 0; r < 4; r++)
            sqi[m][r] = sq[(int)i0 + wr * 64 + m * 16 + kg * 4 + r];   // always < N
    float sqj[4];
#pragma unroll
    for (int n = 0; n < 4; n++) {
        int gj = (int)j0 + wc * 64 + n * 16 + l15;
        sqj[n] = (gj < N_NODES) ? sq[gj] : 0.f;
    }

    // ---- epilogue: d2 -> S (32-col chunks), per-row serial top-8 ----
    float* S = (float*)lds;   // [128][33] = 16.9KB
#pragma unroll
    for (int cs = 0; cs < 8; cs++) {
        __syncthreads();
        if (wc == (cs >> 1)) {
            const int n0 = (cs & 1) * 2;
#pragma unroll
            for (int m = 0; m < 4; m++)
#pragma unroll
                for (int nn = 0; nn < 2; nn++)
#pragma unroll
                    for (int r = 0; r < 4; r++) {
                        int row = wr * 64 + m * 16 + kg * 4 + r;
                        float d2 = sqi[m][r] + sqj[n0 + nn] - 2.f * acc[m][n0 + nn][r];
                        S[row * 33 + nn * 16 + l15] = d2;
                    }
        }
        __syncthreads();
        if (tid < TMG) {
            int r = tid, gi = (int)i0 + r;
            int cbase = (int)j0 + cs * 32;
#pragma unroll 4
            for (int jj = 0; jj < 32; jj++) {
                int gj = cbase + jj;
                if (gj >= N_NODES || gj == gi) continue;
                float v = S[r * 33 + jj];
                float wv = topv[r][7]; int wi = topi[r][7];
                if (v < wv || (v == wv && gj < wi)) {
                    int pos = 7;
                    while (pos > 0) {
                        float pv = topv[r][pos - 1]; int pi = topi[r][pos - 1];
                        if (v < pv || (v == pv && gj < pi)) {
                            topv[r][pos] = pv; topi[r][pos] = (unsigned short)pi; pos--;
                        } else break;
                    }
                    topv[r][pos] = v; topi[r][pos] = (unsigned short)gj;
                }
            }
        }
    }
    __syncthreads();
    if (tid < TMG) {
        int gi = (int)i0 + tid;
#pragma unroll
        for (int k = 0; k < 8; k++) {
            candv[(size_t)gi * NSLOT + t * 8 + k] = topv[tid][k];
            candi[(size_t)gi * NSLOT + t * 8 + k] = (int)topi[tid][k];
        }
    }
}

// ------------- merge 25 sorted 8-lists -> knn (wave per node, lex (v,idx)) -----
__global__ __launch_bounds__(256) void merge_topk_kernel(
        const float* __restrict__ candv, const int* __restrict__ candi,
        int* __restrict__ knn) {
    int node = blockIdx.x * 4 + (threadIdx.x >> 6);
    int lane = threadIdx.x & 63;
    const float* cv = candv + (size_t)node * NSLOT;
    const int*   ci = candi + (size_t)node * NSLOT;
    float v[4]; int ix[4];
#pragma unroll
    for (int u = 0; u < 4; u++) {
        int s = u * 64 + lane;
        bool ok = (s < NSLOT);
        v[u]  = ok ? cv[s] : 3.4e38f;
        ix[u] = ok ? ci[s] : 0x7fffffff;
    }
#pragma unroll 1
    for (int k = 0; k < 8; k++) {
        float bv = v[0]; int bi = ix[0];
#pragma unroll
        for (int u = 1; u < 4; u++)
            if (v[u] < bv || (v[u] == bv && ix[u] < bi)) { bv = v[u]; bi = ix[u]; }
#pragma unroll
        for (int off = 32; off; off >>= 1) {
            float ov = __shfl_xor(bv, off, 64);
            int   oi = __shfl_xor(bi, off, 64);
            if (ov < bv || (ov == bv && oi < bi)) { bv = ov; bi = oi; }
        }
        if (lane == 0) knn[(size_t)node * 8 + k] = bi;
#pragma unroll
        for (int u = 0; u < 4; u++)
            if (ix[u] == bi) { v[u] = 3.4e38f; ix[u] = 0x7fffffff; }
    }
}

// ------------- graph build -------------
__global__ __launch_bounds__(256) void graph_init_kernel(int* deg, int* cnt) {
    int i = blockIdx.x * 256 + threadIdx.x;
    if (i < N_NODES) { deg[i] = 1; cnt[i] = 0; }
}
__global__ __launch_bounds__(256) void deg_count_kernel(const int* __restrict__ knn,
                                                        int* deg) {
    int e = blockIdx.x * 256 + threadIdx.x;
    if (e < N_NODES * 8) atomicAdd(&deg[knn[e]], 1);
}
__global__ __launch_bounds__(256) void dinv_kernel(const int* __restrict__ deg,
                                                   float* __restrict__ dinv) {
    int i = blockIdx.x * 256 + threadIdx.x;
    if (i < N_NODES) dinv[i] = rsqrtf((float)deg[i]);
}
__global__ __launch_bounds__(256) void scan_kernel(const int* __restrict__ deg,
                                                   int* __restrict__ row_ptr) {
    __shared__ int partial[256];
    const int CHUNK = (N_NODES + 255) / 256;
    int tid = threadIdx.x;
    int start = tid * CHUNK;
    int end = start + CHUNK; if (end > N_NODES) end = N_NODES;
    int s = 0;
    for (int i = start; i < end; i++) s += deg[i];
    partial[tid] = s;
    __syncthreads();
    if (tid == 0) {
        int run = 0;
        for (int k = 0; k < 256; k++) { int v = partial[k]; partial[k] = run; run += v; }
        row_ptr[N_NODES] = run;
    }
    __syncthreads();
    int run = partial[tid];
    for (int i = start; i < end; i++) { row_ptr[i] = run; run += deg[i]; }
}
__global__ __launch_bounds__(256) void scatter_kernel(const int* __restrict__ knn,
        const int* __restrict__ row_ptr, int* cnt, int* __restrict__ col) {
    int i = blockIdx.x * 256 + threadIdx.x;
    if (i >= N_NODES) return;
    int ptr = row_ptr[i] + atomicAdd(&cnt[i], 1);
    col[ptr] = i;                                   // self-loop
#pragma unroll
    for (int j = 0; j < 8; j++) {
        int d = knn[(size_t)i * 8 + j];
        int q = row_ptr[d] + atomicAdd(&cnt[d], 1);
        col[q] = i;
    }
}

// ------------- fp16 MFMA GEMM  C[M,N] = A[M,K] @ Bt[N,K]^T  (f32 out) --------
__global__ __launch_bounds__(256) void hgemm_nt_kernel(
        const _Float16* __restrict__ A, const _Float16* __restrict__ Bt,
        float* __restrict__ C, int M, int N, int K) {
    __shared__ char Alds[16384], Blds[16384];
    int tid = threadIdx.x, lane = tid & 63, wave = tid >> 6;
    int wr = wave >> 1, wc = wave & 1;
    int l15 = lane & 15, kg = lane >> 4;
    int nt = N >> 7;
    int i0 = (blockIdx.x / nt) * 128, j0 = (blockIdx.x % nt) * 128;
    f32x4 acc[4][4] = {};

#pragma unroll 1
    for (int kk = 0; kk < K; kk += 64) {
        __syncthreads();
#pragma unroll
        for (int g = 0; g < 4; g++) {
            int R = wave * 32 + g * 8;
            int swzk = ((lane & 7) ^ (lane >> 3)) << 3;
            const _Float16* ga = A + (size_t)(i0 + R + (lane >> 3)) * K + kk + swzk;
            gld_lds16(ga, Alds + R * 128);
            const _Float16* gb = Bt + (size_t)(j0 + R + (lane >> 3)) * K + kk + swzk;
            gld_lds16(gb, Blds + R * 128);
        }
        __syncthreads();
#pragma unroll
        for (int s = 0; s < 2; s++) {
            half8 a[4], b[4];
#pragma unroll
            for (int m = 0; m < 4; m++) a[m] = frag_read(Alds, wr * 64 + m * 16 + l15, s, lane);
#pragma unroll
            for (int n = 0; n < 4; n++) b[n] = frag_read(Blds, wc * 64 + n * 16 + l15, s, lane);
#pragma unroll
            for (int m = 0; m < 4; m++)
#pragma unroll
                for (int n = 0; n < 4; n++)
                    acc[m][n] = __builtin_amdgcn_mfma_f32_16x16x32_f16(a[m], b[n], acc[m][n], 0, 0, 0);
        }
    }
#pragma unroll
    for (int m = 0; m < 4; m++)
#pragma unroll
        for (int n = 0; n < 4; n++)
#pragma unroll
            for (int r = 0; r < 4; r++) {
                int row = i0 + wr * 64 + m * 16 + kg * 4 + r;
                int colj = j0 + wc * 64 + n * 16 + l15;
                C[(size_t)row * N + colj] = acc[m][n][r];
            }
}

// ------------- GCN aggregation: out[d] = relu(dinv[d]*sum hw[s]*dinv[s] + b) ---
template <bool HALF>
__global__ __launch_bounds__(256) void aggregate_kernel(
        const float* __restrict__ hw, const int* __restrict__ row_ptr,
        const int* __restrict__ col, const float* __restrict__ dinv,
        const float* __restrict__ bias, void* __restrict__ outp) {
    int node = blockIdx.x * 4 + (threadIdx.x >> 6);
    int lane = threadIdx.x & 63;
    int e0 = row_ptr[node], e1 = row_ptr[node + 1];
    float4 acc0 = {0.f, 0.f, 0.f, 0.f}, acc1 = {0.f, 0.f, 0.f, 0.f};
    for (int e = e0; e < e1; e++) {
        int s = col[e];
        float w = dinv[s];
        const float* hr = hw + (size_t)s * ODIM;
        float4 v0 = *(const float4*)(hr + lane * 4);
        float4 v1 = *(const float4*)(hr + 256 + lane * 4);
        acc0.x = fmaf(w, v0.x, acc0.x); acc0.y = fmaf(w, v0.y, acc0.y);
        acc0.z = fmaf(w, v0.z, acc0.z); acc0.w = fmaf(w, v0.w, acc0.w);
        acc1.x = fmaf(w, v1.x, acc1.x); acc1.y = fmaf(w, v1.y, acc1.y);
        acc1.z = fmaf(w, v1.z, acc1.z); acc1.w = fmaf(w, v1.w, acc1.w);
    }
    float wd = dinv[node];
    float4 b0 = *(const float4*)(bias + lane * 4);
    float4 b1 = *(const float4*)(bias + 256 + lane * 4);
    float o[8];
    o[0] = fmaxf(fmaf(acc0.x, wd, b0.x), 0.f);
    o[1] = fmaxf(fmaf(acc0.y, wd, b0.y), 0.f);
    o[2] = fmaxf(fmaf(acc0.z, wd, b0.z), 0.f);
    o[3] = fmaxf(fmaf(acc0.w, wd, b0.w), 0.f);
    o[4] = fmaxf(fmaf(acc1.x, wd, b1.x), 0.f);
    o[5] = fmaxf(fmaf(acc1.y, wd, b1.y), 0.f);
    o[6] = fmaxf(fmaf(acc1.z, wd, b1.z), 0.f);
    o[7] = fmaxf(fmaf(acc1.w, wd, b1.w), 0.f);
    if (HALF) {
        _Float16* out = (_Float16*)outp;
        half4 h0, h1;
#pragma unroll
        for (int j = 0; j < 4; j++) { h0[j] = (_Float16)o[j]; h1[j] = (_Float16)o[4 + j]; }
        *(half4*)(out + (size_t)node * ODIM + lane * 4)       = h0;
        *(half4*)(out + (size_t)node * ODIM + 256 + lane * 4) = h1;
    } else {
        float* out = (float*)outp;
        float4 f0 = {o[0], o[1], o[2], o[3]}, f1 = {o[4], o[5], o[6], o[7]};
        *(float4*)(out + (size_t)node * ODIM + lane * 4)       = f0;
        *(float4*)(out + (size_t)node * ODIM + 256 + lane * 4) = f1;
    }
}

extern "C" void kernel_launch(void* const* d_in, const int* in_sizes, int n_in,
                              void* d_out, int out_size, void* d_ws, size_t ws_size,
                              hipStream_t stream) {
    const float* x  = (const float*)d_in[0];
    const float* W1 = (const float*)d_in[1];
    const float* b1 = (const float*)d_in[2];
    const float* W2 = (const float*)d_in[3];
    const float* b2 = (const float*)d_in[4];
    float* out = (float*)d_out;
    char* ws = (char*)d_ws;

    _Float16* xhi  = (_Float16*)(ws + XHI_OFF);
    _Float16* xlo  = (_Float16*)(ws + XLO_OFF);
    float* candv   = (float*)(ws + CANDV_OFF);
    int*   candi   = (int*)  (ws + CANDI_OFF);
    float* sq      = (float*)(ws + SQ_OFF);
    int*   knn     = (int*)  (ws + KNN_OFF);
    int*   deg     = (int*)  (ws + DEG_OFF);
    int*   cnt     = (int*)  (ws + CNT_OFF);
    float* dinv    = (float*)(ws + DINV_OFF);
    int*   row_ptr = (int*)  (ws + RPTR_OFF);
    int*   col     = (int*)  (ws + COL_OFF);
    _Float16* w1t  = (_Float16*)(ws + W1T_OFF);
    _Float16* w2t  = (_Float16*)(ws + W2T_OFF);
    float* hw      = (float*)(ws + HW_OFF);       // reuses xlo region (post-gram)
    _Float16* h1h  = (_Float16*)(ws + H1H_OFF);   // reuses xlo region (post-gram)

    conv_split_kernel<<<12544, 256, 0, stream>>>(x, xhi, xlo);
    sq_kernel<<<N_NODES, 64, 0, stream>>>(x, sq);
    wtrans_kernel<<<dim3(CDIM / 64, ODIM / 64), 256, 0, stream>>>(W1, w1t, CDIM, ODIM);
    wtrans_kernel<<<dim3(ODIM / 64, ODIM / 64), 256, 0, stream>>>(W2, w2t, ODIM, ODIM);

    gram_topk_mfma<<<GRID_G, 512, 0, stream>>>(xhi, xlo, sq, candv, candi);
    merge_topk_kernel<<<N_NODES / 4, 256, 0, stream>>>(candv, candi, knn);

    graph_init_kernel<<<(N_NODES + 255) / 256, 256, 0, stream>>>(deg, cnt);
    deg_count_kernel<<<(N_NODES * 8) / 256, 256, 0, stream>>>(knn, deg);
    dinv_kernel<<<(N_NODES + 255) / 256, 256, 0, stream>>>(deg, dinv);
    scan_kernel<<<1, 256, 0, stream>>>(deg, row_ptr);
    scatter_kernel<<<(N_NODES + 255) / 256, 256, 0, stream>>>(knn, row_ptr, cnt, col);

    hgemm_nt_kernel<<<(N_NODES / 128) * (ODIM / 128), 256, 0, stream>>>(xhi, w1t, hw, N_NODES, ODIM, CDIM);
    aggregate_kernel<true><<<N_NODES / 4, 256, 0, stream>>>(hw, row_ptr, col, dinv, b1, (void*)h1h);
    hgemm_nt_kernel<<<(N_NODES / 128) * (ODIM / 128), 256, 0, stream>>>(h1h, w2t, hw, N_NODES, ODIM, ODIM);
    aggregate_kernel<false><<<N_NODES / 4, 256, 0, stream>>>(hw, row_ptr, col, dinv, b2, (void*)out);
}